// Round 1
// baseline (1230.520 us; speedup 1.0000x reference)
//
#include <hip/hip_runtime.h>

// MissHitScatter: PATH_NUM=4, IS_HIT=true -> out[0] = inputs, out[1..3] = 0.
// inputs: [65536, 1024] fp32; out: [4, 65536, 1024] fp32.
//
// Split into the two pure streaming primitives this chip is proven to run at
// ~6.2-6.3 TB/s (rocclr fill = 6.2 TB/s @ 10% occupancy; float4 copy = 6.29):
//   1) copy kernel : out[0 .. 256MiB)      = in        (read 268MB, write 268MB)
//   2) zero kernel : out[256MiB .. 1GiB)   = 0         (write 805MB, no reads)
// The previous single mixed kernel ran the same 1.342 GB at only ~2.9 TB/s.

typedef float f32x4 __attribute__((ext_vector_type(4)));

__global__ __launch_bounds__(256) void MissHit_copy(
    const f32x4* __restrict__ in, f32x4* __restrict__ out, unsigned int n_vec) {
  unsigned int stride = gridDim.x * blockDim.x;
  unsigned int i = blockIdx.x * blockDim.x + threadIdx.x;
  #pragma unroll 4
  for (; i < n_vec; i += stride) {
    f32x4 v = __builtin_nontemporal_load(&in[i]);
    __builtin_nontemporal_store(v, &out[i]);
  }
}

__global__ __launch_bounds__(256) void MissHit_zero(
    f32x4* __restrict__ out, unsigned int n_vec) {
  unsigned int stride = gridDim.x * blockDim.x;
  unsigned int i = blockIdx.x * blockDim.x + threadIdx.x;
  f32x4 z = {0.0f, 0.0f, 0.0f, 0.0f};
  #pragma unroll 4
  for (; i < n_vec; i += stride) {
    __builtin_nontemporal_store(z, &out[i]);
  }
}

extern "C" void kernel_launch(void* const* d_in, const int* in_sizes, int n_in,
                              void* d_out, int out_size, void* d_ws, size_t ws_size,
                              hipStream_t stream) {
  const f32x4* in = (const f32x4*)d_in[0];
  f32x4* out = (f32x4*)d_out;

  // in_sizes[0] = 65536*1024 = 67,108,864 floats; out_size = 4x that.
  unsigned int n_vec_in   = (unsigned int)(in_sizes[0] / 4);  // 16,777,216 float4
  unsigned int n_vec_out  = (unsigned int)(out_size / 4);     // 67,108,864 float4
  unsigned int n_vec_zero = n_vec_out - n_vec_in;             // 50,331,648 float4

  const int block = 256;
  // 2048 blocks x 4 waves = 8192 waves = exactly the chip's 256 CU x 32 wave
  // slots; grid-stride covers the rest. Memory-bound: more blocks adds nothing
  // (poison fill hits 78% peak at 10% occupancy).
  const int grid_copy = 2048;   // 16,777,216 / (2048*256) = 32 iters/thread
  const int grid_zero = 2048;   // 50,331,648 / (2048*256) = 96 iters/thread

  MissHit_copy<<<grid_copy, block, 0, stream>>>(in, out, n_vec_in);
  MissHit_zero<<<grid_zero, block, 0, stream>>>(out + n_vec_in, n_vec_zero);
}

// Round 2
// 1167.179 us; speedup vs baseline: 1.0543x; 1.0543x over previous
//
#include <hip/hip_runtime.h>

// MissHitScatter: PATH_NUM=4, IS_HIT=true -> out[0] = inputs, out[1..3] = 0.
// inputs: [65536, 1024] fp32; out: [4, 65536, 1024] fp32.
//
// Round-1 lesson: nontemporal stores REGRESSED the pure-write stream (~70 us).
// The rocclr fill kernel (plain stores) sustains 6.2 TB/s on this exact chip,
// so delegate the zero region to hipMemsetAsync (stream-ordered, graph-safe)
// and keep the copy as a plain cached float4 stream:
//   1) copy kernel   : out[0 .. 268MB)   = in   (read 268MB, write 268MB, ~90us)
//   2) hipMemsetAsync: out[268MB .. 1.07GB) = 0 (write 805MB, ~130us @ 6.2TB/s)

typedef float f32x4 __attribute__((ext_vector_type(4)));

__global__ __launch_bounds__(256) void MissHit_copy(
    const f32x4* __restrict__ in, f32x4* __restrict__ out, unsigned int n_vec) {
  unsigned int i = blockIdx.x * blockDim.x + threadIdx.x;
  if (i < n_vec) {
    out[i] = in[i];   // plain cached load/store; fully coalesced 16B/lane
  }
}

extern "C" void kernel_launch(void* const* d_in, const int* in_sizes, int n_in,
                              void* d_out, int out_size, void* d_ws, size_t ws_size,
                              hipStream_t stream) {
  const f32x4* in = (const f32x4*)d_in[0];
  f32x4* out = (f32x4*)d_out;

  // in_sizes[0] = 65536*1024 = 67,108,864 floats; out_size = 4x that.
  unsigned int n_vec_in  = (unsigned int)(in_sizes[0] / 4);   // 16,777,216 float4
  unsigned int n_floats_zero = (unsigned int)(out_size - in_sizes[0]); // 201,326,592

  const int block = 256;
  unsigned int grid_copy = (n_vec_in + block - 1) / block;    // 65,536 blocks

  MissHit_copy<<<grid_copy, block, 0, stream>>>(in, out, n_vec_in);

  // Zero paths 1..3 via the runtime's fill path (proven 6.2 TB/s on this chip).
  hipMemsetAsync((void*)((float*)d_out + (size_t)in_sizes[0]), 0,
                 (size_t)n_floats_zero * sizeof(float), stream);
}